// Round 6
// baseline (41.923 us; speedup 1.0000x reference)
//
#include <hip/hip_runtime.h>

#define H 128
#define W 128
#define Zd 16
#define C 20
#define HWZ (H * W * Zd)
#define NXCD 8

typedef float f4 __attribute__((ext_vector_type(4)));

__device__ __forceinline__ f4 load4(const float* p) { return *(const f4*)p; }
__device__ __forceinline__ f4 load4u(const float* p) {
    f4 r;
    __builtin_memcpy(&r, p, 16);
    return r;
}
__device__ __forceinline__ float bf2f(unsigned short u) {
    unsigned v = ((unsigned)u) << 16;
    float f;
    __builtin_memcpy(&f, &v, 4);
    return f;
}
__device__ __forceinline__ unsigned short f2bf(float f) {
    unsigned u;
    __builtin_memcpy(&u, &f, 4);
    u = (u + 0x7fff + ((u >> 16) & 1)) >> 16;  // round-to-nearest-even
    return (unsigned short)u;
}

// ---------------- X step, row-based: one block = half h-row (64 w x 4 z4),
// gates normalized ONCE per position, then all 20 channels.
// grid = 256: xcd = bid&7 owns rows [16*xcd, 16*xcd+16)
__global__ __launch_bounds__(256) void prop_x(const float* __restrict__ gd,
                                              const float* __restrict__ in,
                                              float* __restrict__ out) {
    const int bid = blockIdx.x;
    const int xcd = bid & (NXCD - 1);
    const int i = bid >> 3;              // 0..31
    const int h = (xcd << 4) + (i >> 1); // 16 rows per XCD
    const int t = threadIdx.x;
    const int z4 = (t & 3) << 2;
    const int w = ((i & 1) << 6) + (t >> 2);  // half-row

    const int DI[8] = {1, 1, 1, 0, 0, -1, -1, -1};
    const int DJ[8] = {1, 0, -1, 1, -1, 1, 0, -1};

    f4 g[8];
    int noff[8];
    f4 A = {0, 0, 0, 0}, S = {0, 0, 0, 0};
#pragma unroll
    for (int k = 0; k < 8; ++k) {
        int hh = h + DI[k], ww = w + DJ[k];
        bool valid = ((unsigned)hh < H) && ((unsigned)ww < W);
        f4 val = {0, 0, 0, 0};
        if (valid) val = load4(gd + ((k * H + hh) * W + ww) * Zd + z4);
        g[k] = val;
        noff[k] = valid ? (DI[k] * W + DJ[k]) * Zd : 0;
#pragma unroll
        for (int e = 0; e < 4; ++e) A[e] += __builtin_fabsf(val[e]);
        S += val;
    }
    f4 invA = 1.0f / A;
    f4 c0 = 1.0f - S * invA;
#pragma unroll
    for (int k = 0; k < 8; ++k) g[k] *= invA;

    const int base = (h * W + w) * Zd + z4;
#pragma unroll 5
    for (int c = 0; c < C; ++c) {
        const float* pc = in + c * HWZ + base;
        f4 acc = c0 * load4(pc);
#pragma unroll
        for (int k = 0; k < 8; ++k) acc += g[k] * load4(pc + noff[k]);
        *(f4*)(out + c * HWZ + base) = acc;
    }
}

// ---------------- Fused Y+Z: one block = one h-row x 10 channels (CGF=2).
// Y-out row kept in LDS as bf16 (40 KB). grid = 256: xcd x cg(2) x row(16).
#define CPGF 10
__global__ __launch_bounds__(512) void prop_yz(const float* __restrict__ gd,
                                               const float* __restrict__ in,
                                               float* __restrict__ out) {
    const int bid = blockIdx.x;
    const int xcd = bid & (NXCD - 1);
    const int i = bid >> 3;              // 0..31
    const int cg = i & 1;
    const int h = (xcd << 4) + (i >> 1);

    const int t = threadIdx.x;  // 0..511
    const int z4 = (t & 3) << 2;
    const int w = t >> 2;       // 0..127

    __shared__ unsigned short yout[CPGF][W][Zd];  // 40 KB bf16

    const int DI[8] = {1, 1, 1, 0, 0, -1, -1, -1};
    const int DJ[8] = {1, 0, -1, 1, -1, 1, 0, -1};
    const int base = (h * W + w) * Zd + z4;
    const int loo = (z4 == 0) ? 0 : -1;
    const int hio = (z4 == 12) ? 3 : 4;

    // ======== Y step (gates 8..15, row = h, row stride W*Zd) ========
    {
        const int gbase = (((8 * H) + h) * W + w) * Zd + z4;
        f4 g[8];
        f4 A = {0, 0, 0, 0}, S = {0, 0, 0, 0};
#pragma unroll
        for (int k = 0; k < 8; ++k) {
            int di = DI[k], dj = DJ[k];
            bool rv = (unsigned)(h + di) < H;
            f4 val = {0, 0, 0, 0};
            if (rv) {
                val = (dj == 0) ? load4(gd + gbase + k * HWZ + di * (W * Zd))
                                : load4u(gd + gbase + k * HWZ + di * (W * Zd) + dj);
                if (dj == -1 && z4 == 0) val[0] = 0.f;
                if (dj == 1 && z4 == 12) val[3] = 0.f;
            }
            g[k] = val;
#pragma unroll
            for (int e = 0; e < 4; ++e) A[e] += __builtin_fabsf(val[e]);
            S += val;
        }
        f4 invA = 1.0f / A;
        f4 c0 = 1.0f - S * invA;
#pragma unroll
        for (int k = 0; k < 8; ++k) g[k] *= invA;

        f4 gp[3] = {g[0], g[3], g[5]};
        f4 gc[3] = {g[1], c0, g[6]};
        f4 gm[3] = {g[2], g[4], g[7]};
        const int DIr[3] = {1, 0, -1};
        int rowoff[3];
#pragma unroll
        for (int r = 0; r < 3; ++r)
            rowoff[r] = ((unsigned)(h + DIr[r]) < H) ? DIr[r] * (W * Zd) : 0;

#pragma unroll 2
        for (int cc = 0; cc < CPGF; ++cc) {
            const int c = cg * CPGF + cc;
            const float* pc = in + c * HWZ + base;
            f4 acc = {0, 0, 0, 0};
#pragma unroll
            for (int r = 0; r < 3; ++r) {
                const float* pr = pc + rowoff[r];
                f4 v = load4(pr);
                float lo = pr[loo];
                float hi = pr[hio];
                f4 tm = {lo, v[0], v[1], v[2]};
                f4 tp = {v[1], v[2], v[3], hi};
                acc += gm[r] * tm + gc[r] * v + gp[r] * tp;
            }
            unsigned short us[4];
#pragma unroll
            for (int e = 0; e < 4; ++e) us[e] = f2bf(acc[e]);
            unsigned long long packed;
            __builtin_memcpy(&packed, us, 8);
            *(unsigned long long*)(&yout[cc][w][z4]) = packed;
        }
    }

    __syncthreads();

    // ======== Z step (gates 16..23, row = w, row stride Zd) ========
    {
        const int gbase = (((16 * H) + h) * W + w) * Zd + z4;
        f4 g[8];
        f4 A = {0, 0, 0, 0}, S = {0, 0, 0, 0};
#pragma unroll
        for (int k = 0; k < 8; ++k) {
            int di = DI[k], dj = DJ[k];
            bool rv = (unsigned)(w + di) < W;
            f4 val = {0, 0, 0, 0};
            if (rv) {
                val = (dj == 0) ? load4(gd + gbase + k * HWZ + di * Zd)
                                : load4u(gd + gbase + k * HWZ + di * Zd + dj);
                if (dj == -1 && z4 == 0) val[0] = 0.f;
                if (dj == 1 && z4 == 12) val[3] = 0.f;
            }
            g[k] = val;
#pragma unroll
            for (int e = 0; e < 4; ++e) A[e] += __builtin_fabsf(val[e]);
            S += val;
        }
        f4 invA = 1.0f / A;
        f4 c0 = 1.0f - S * invA;
#pragma unroll
        for (int k = 0; k < 8; ++k) g[k] *= invA;

        f4 gp[3] = {g[0], g[3], g[5]};
        f4 gc[3] = {g[1], c0, g[6]};
        f4 gm[3] = {g[2], g[4], g[7]};
        const int DIr[3] = {1, 0, -1};
        int woff[3];  // LDS ushort offset for row w+di
#pragma unroll
        for (int r = 0; r < 3; ++r)
            woff[r] = ((unsigned)(w + DIr[r]) < W) ? DIr[r] * Zd : 0;

#pragma unroll 2
        for (int cc = 0; cc < CPGF; ++cc) {
            const int c = cg * CPGF + cc;
            const unsigned short* pl = &yout[cc][w][z4];
            f4 acc = {0, 0, 0, 0};
#pragma unroll
            for (int r = 0; r < 3; ++r) {
                const unsigned short* pr = pl + woff[r];
                f4 v = {bf2f(pr[0]), bf2f(pr[1]), bf2f(pr[2]), bf2f(pr[3])};
                float lo = bf2f(pr[loo]);
                float hi = bf2f(pr[hio]);
                f4 tm = {lo, v[0], v[1], v[2]};
                f4 tp = {v[1], v[2], v[3], hi};
                acc += gm[r] * tm + gc[r] * v + gp[r] * tp;
            }
            *(f4*)(out + c * HWZ + base) = acc;
        }
    }
}

extern "C" void kernel_launch(void* const* d_in, const int* in_sizes, int n_in,
                              void* d_out, int out_size, void* d_ws, size_t ws_size,
                              hipStream_t stream) {
    const float* gd = (const float*)d_in[0];   // guidance (24,128,128,16) f32
    const float* blur = (const float*)d_in[1]; // blur (20,128,128,16) f32
    float* out = (float*)d_out;                // (20,128,128,16) f32
    float* ws = (float*)d_ws;

    prop_x<<<dim3(256), dim3(256), 0, stream>>>(gd, blur, ws); // X: blur -> ws
    prop_yz<<<dim3(256), dim3(512), 0, stream>>>(gd, ws, out); // Y+Z: ws -> out
}

// Round 7
// 35.266 us; speedup vs baseline: 1.1888x; 1.1888x over previous
//
#include <hip/hip_runtime.h>

#define H 128
#define W 128
#define Zd 16
#define C 20
#define HWZ (H * W * Zd)
#define NXCD 8

typedef float f4 __attribute__((ext_vector_type(4)));

__device__ __forceinline__ f4 load4(const float* p) { return *(const f4*)p; }
__device__ __forceinline__ f4 load4u(const float* p) {
    f4 r;
    __builtin_memcpy(&r, p, 16);
    return r;
}

// ---------------- X step v3: block = 64 pos-f4 (16 w x 4 z4) x 4 cgroups.
// Wave 0 computes normalized gates once per position -> LDS; all 4 waves then
// process 5 channels each. grid = 1024: xcd=bid&7 owns rows [16x,16x+16).
__global__ __launch_bounds__(256, 6) void prop_x(const float* __restrict__ gd,
                                                 const float* __restrict__ in,
                                                 float* __restrict__ out) {
    const int bid = blockIdx.x;
    const int xcd = bid & (NXCD - 1);
    const int j = bid >> 3;               // 0..127
    const int h = (xcd << 4) + (j >> 3);  // 16 rows per XCD
    const int wbase = (j & 7) << 4;       // 8 w-tiles of 16

    const int t = threadIdx.x;
    const int p = t & 63;                 // position within tile
    const int cg = t >> 6;                // 0..3 (5 channels each)
    const int z4 = (p & 3) << 2;
    const int w = wbase + (p >> 2);

    const int DI[8] = {1, 1, 1, 0, 0, -1, -1, -1};
    const int DJ[8] = {1, 0, -1, 1, -1, 1, 0, -1};

    __shared__ f4 xg[9][64];   // 9 KB: g[0..7] + c0 per position

    if (t < 64) {   // wave 0: gates for its position p=t
        f4 g[8];
        f4 A = {0, 0, 0, 0}, S = {0, 0, 0, 0};
#pragma unroll
        for (int k = 0; k < 8; ++k) {
            int hh = h + DI[k], ww = w + DJ[k];
            bool valid = ((unsigned)hh < H) && ((unsigned)ww < W);
            f4 val = {0, 0, 0, 0};
            if (valid) val = load4(gd + ((k * H + hh) * W + ww) * Zd + z4);
            g[k] = val;
#pragma unroll
            for (int e = 0; e < 4; ++e) A[e] += __builtin_fabsf(val[e]);
            S += val;
        }
        f4 invA = 1.0f / A;
        f4 c0 = 1.0f - S * invA;
#pragma unroll
        for (int k = 0; k < 8; ++k) xg[k][t] = g[k] * invA;
        xg[8][t] = c0;
    }
    __syncthreads();

    f4 g[8], c0v;
#pragma unroll
    for (int k = 0; k < 8; ++k) g[k] = xg[k][p];
    c0v = xg[8][p];

    int noff[8];
#pragma unroll
    for (int k = 0; k < 8; ++k) {
        int hh = h + DI[k], ww = w + DJ[k];
        bool valid = ((unsigned)hh < H) && ((unsigned)ww < W);
        noff[k] = valid ? (DI[k] * W + DJ[k]) * Zd : 0;
    }

    const int base = (h * W + w) * Zd + z4;
#pragma unroll
    for (int cc = 0; cc < 5; ++cc) {
        const int c = cg * 5 + cc;
        const float* pc = in + c * HWZ + base;
        f4 acc = c0v * load4(pc);
#pragma unroll
        for (int k = 0; k < 8; ++k) acc += g[k] * load4(pc + noff[k]);
        *(f4*)(out + c * HWZ + base) = acc;
    }
}

// ---------------- Fused Y+Z (round-5 version, unchanged): one block owns one
// h-row (full W x Z) x 5 channels; Y-out row in f32 LDS; Z reads LDS.
#define CPGF 5
__global__ __launch_bounds__(512) void prop_yz(const float* __restrict__ gd,
                                               const float* __restrict__ in,
                                               float* __restrict__ out) {
    // grid = 512 blocks: xcd(8) x cgf(4) x rowin(16); XCD x owns rows [16x,16x+16)
    const int bid = blockIdx.x;
    const int xcd = bid & (NXCD - 1);
    const int i = bid >> 3;     // 0..63
    const int cgf = i >> 4;     // 0..3
    const int h = (xcd << 4) + (i & 15);

    const int t = threadIdx.x;  // 0..511
    const int z4 = (t & 3) << 2;
    const int w = t >> 2;       // 0..127

    __shared__ float yout[CPGF][W][Zd];   // 40 KB

    const int DI[8] = {1, 1, 1, 0, 0, -1, -1, -1};
    const int DJ[8] = {1, 0, -1, 1, -1, 1, 0, -1};
    const int base = (h * W + w) * Zd + z4;
    const int loo = (z4 == 0) ? 0 : -1;
    const int hio = (z4 == 12) ? 3 : 4;

    // ======== Y step (gates 8..15, row = h, row stride W*Zd) ========
    {
        const int gbase = (((8 * H) + h) * W + w) * Zd + z4;
        f4 g[8];
        f4 A = {0, 0, 0, 0}, S = {0, 0, 0, 0};
#pragma unroll
        for (int k = 0; k < 8; ++k) {
            int di = DI[k], dj = DJ[k];
            bool rv = (unsigned)(h + di) < H;
            f4 val = {0, 0, 0, 0};
            if (rv) {
                val = (dj == 0) ? load4(gd + gbase + k * HWZ + di * (W * Zd))
                                : load4u(gd + gbase + k * HWZ + di * (W * Zd) + dj);
                if (dj == -1 && z4 == 0) val[0] = 0.f;
                if (dj == 1 && z4 == 12) val[3] = 0.f;
            }
            g[k] = val;
#pragma unroll
            for (int e = 0; e < 4; ++e) A[e] += __builtin_fabsf(val[e]);
            S += val;
        }
        f4 invA = 1.0f / A;
        f4 c0 = 1.0f - S * invA;
#pragma unroll
        for (int k = 0; k < 8; ++k) g[k] *= invA;

        f4 gp[3] = {g[0], g[3], g[5]};
        f4 gc[3] = {g[1], c0, g[6]};
        f4 gm[3] = {g[2], g[4], g[7]};
        const int DIr[3] = {1, 0, -1};
        int rowoff[3];
#pragma unroll
        for (int r = 0; r < 3; ++r)
            rowoff[r] = ((unsigned)(h + DIr[r]) < H) ? DIr[r] * (W * Zd) : 0;

#pragma unroll
        for (int cc = 0; cc < CPGF; ++cc) {
            const int c = cgf * CPGF + cc;
            const float* pc = in + c * HWZ + base;
            f4 acc = {0, 0, 0, 0};
#pragma unroll
            for (int r = 0; r < 3; ++r) {
                const float* pr = pc + rowoff[r];
                f4 v = load4(pr);
                float lo = pr[loo];
                float hi = pr[hio];
                f4 tm = {lo, v[0], v[1], v[2]};
                f4 tp = {v[1], v[2], v[3], hi};
                acc += gm[r] * tm + gc[r] * v + gp[r] * tp;
            }
            *(f4*)(&yout[cc][w][z4]) = acc;
        }
    }

    __syncthreads();

    // ======== Z step (gates 16..23, row = w, row stride Zd) ========
    {
        const int gbase = (((16 * H) + h) * W + w) * Zd + z4;
        f4 g[8];
        f4 A = {0, 0, 0, 0}, S = {0, 0, 0, 0};
#pragma unroll
        for (int k = 0; k < 8; ++k) {
            int di = DI[k], dj = DJ[k];
            bool rv = (unsigned)(w + di) < W;
            f4 val = {0, 0, 0, 0};
            if (rv) {
                val = (dj == 0) ? load4(gd + gbase + k * HWZ + di * Zd)
                                : load4u(gd + gbase + k * HWZ + di * Zd + dj);
                if (dj == -1 && z4 == 0) val[0] = 0.f;
                if (dj == 1 && z4 == 12) val[3] = 0.f;
            }
            g[k] = val;
#pragma unroll
            for (int e = 0; e < 4; ++e) A[e] += __builtin_fabsf(val[e]);
            S += val;
        }
        f4 invA = 1.0f / A;
        f4 c0 = 1.0f - S * invA;
#pragma unroll
        for (int k = 0; k < 8; ++k) g[k] *= invA;

        f4 gp[3] = {g[0], g[3], g[5]};
        f4 gc[3] = {g[1], c0, g[6]};
        f4 gm[3] = {g[2], g[4], g[7]};
        const int DIr[3] = {1, 0, -1};
        int woff[3];  // LDS float offset for row w+di
#pragma unroll
        for (int r = 0; r < 3; ++r)
            woff[r] = ((unsigned)(w + DIr[r]) < W) ? DIr[r] * Zd : 0;

#pragma unroll
        for (int cc = 0; cc < CPGF; ++cc) {
            const int c = cgf * CPGF + cc;
            const float* pl = &yout[cc][w][z4];
            f4 acc = {0, 0, 0, 0};
#pragma unroll
            for (int r = 0; r < 3; ++r) {
                const float* pr = pl + woff[r];
                f4 v = load4(pr);
                float lo = pr[loo];
                float hi = pr[hio];
                f4 tm = {lo, v[0], v[1], v[2]};
                f4 tp = {v[1], v[2], v[3], hi};
                acc += gm[r] * tm + gc[r] * v + gp[r] * tp;
            }
            *(f4*)(out + c * HWZ + base) = acc;
        }
    }
}

extern "C" void kernel_launch(void* const* d_in, const int* in_sizes, int n_in,
                              void* d_out, int out_size, void* d_ws, size_t ws_size,
                              hipStream_t stream) {
    const float* gd = (const float*)d_in[0];   // guidance (24,128,128,16) f32
    const float* blur = (const float*)d_in[1]; // blur (20,128,128,16) f32
    float* out = (float*)d_out;                // (20,128,128,16) f32
    float* ws = (float*)d_ws;

    prop_x<<<dim3(1024), dim3(256), 0, stream>>>(gd, blur, ws); // X: blur -> ws
    prop_yz<<<dim3(512), dim3(512), 0, stream>>>(gd, ws, out);  // Y+Z: ws -> out
}